// Round 18
// baseline (58.360 us; speedup 1.0000x reference)
//
#include <hip/hip_runtime.h>

// SRNet via MFMA (v_mfma_f32_32x32x16_f16), D = W * X^T.
// Round 18: attack EXPOSED LATENCY (the r11-r17 plateau survived changes in
// LDS-read count, occupancy, and ILP -> serial-chain latency is the wall):
//  (a) next-group patch prefetch: the 9 global loads (~200-400cyc L2) issue
//      under the previous group's 6 layers instead of heading the chain.
//  (b) layers 2+3 weight frags hoisted to 64 persistent VGPRs (named array,
//      constant indices; per-iteration clobber does not touch locals) ->
//      in-loop LDS reads 38 -> 22 and zero-latency operands mid-chain.
// Lean r16 body kept: bias as 5th MFMA k-step from 8 persistent regs, b1 in
// layer-1 k=9 column, b6 at store. ~220 total regs -> 2 waves/SIMD, grid 512.

typedef _Float16 f16x8  __attribute__((ext_vector_type(8)));
typedef _Float16 half2v __attribute__((ext_vector_type(2)));
typedef float    f32x16 __attribute__((ext_vector_type(16)));
typedef unsigned int u32;
typedef u32 u32x4 __attribute__((ext_vector_type(4)));

union FragU { f16x8 v; u32 w[4]; };

__device__ __forceinline__ u32 pkrne(float a, float b) {
    half2v h; h.x = (_Float16)a; h.y = (_Float16)b;
    return __builtin_bit_cast(u32, h);
}
__device__ __forceinline__ u32 pkrtz(float a, float b) {
    return __builtin_bit_cast(u32, __builtin_amdgcn_cvt_pkrtz(a, b));
}
__device__ __forceinline__ u32 pk_relu(u32 a) {
    half2v z = {};
    half2v r = __builtin_elementwise_max(__builtin_bit_cast(half2v, a), z);
    return __builtin_bit_cast(u32, r);
}

__device__ __forceinline__ f32x16 mfma16(const FragU& a, const FragU& b, f32x16 c) {
    return __builtin_amdgcn_mfma_f32_32x32x16_f16(a.v, b.v, c, 0, 0, 0);
}

__device__ __forceinline__ void pl32(u32& x, u32& y) {
    auto r = __builtin_amdgcn_permlane32_swap((int)x, (int)y, false, false);
    x = (u32)r[0]; y = (u32)r[1];
}

__device__ __forceinline__ void calc_coords(int g, int m, int& b, int& hp, int& wp) {
    unsigned P = (unsigned)(g * 32 + m);
    unsigned bb = P / 64516u;            // 254*254
    unsigned rem = P - bb * 64516u;
    unsigned h = rem / 254u;
    b = (int)bb; hp = (int)h; wp = (int)(rem - h * 254u);
}

__device__ __forceinline__ void prep_group(const float* __restrict__ x_in,
                                           int g, int m, int lo,
                                           float p[9], u32& ooff) {
    constexpr int OW = 1016;
    int b, hp, wp;
    calc_coords(g, m, b, hp, wp);
    const float* base = x_in + ((size_t)b << 16) + hp * 256 + wp;
#pragma unroll
    for (int i = 0; i < 3; ++i)
#pragma unroll
        for (int j = 0; j < 3; ++j)
            p[i * 3 + j] = base[i * 256 + j];
    ooff = (u32)b * (OW * OW) + (u32)(4 * hp + lo) * OW + 4 * wp;
}

// acc(2 tiles, D-layout, bias already inside) -> f16 -> relu -> permlane -> B
__device__ __forceinline__ void epilogue(const f32x16& A0, const f32x16& A1,
                                         FragU (&B)[4]) {
    u32 ww[2][4][2];
#pragma unroll
    for (int mt = 0; mt < 2; ++mt) {
        const f32x16& A = mt ? A1 : A0;
#pragma unroll
        for (int q = 0; q < 4; ++q) {
            ww[mt][q][0] = pk_relu(pkrtz(A[4 * q + 0], A[4 * q + 1]));
            ww[mt][q][1] = pk_relu(pkrtz(A[4 * q + 2], A[4 * q + 3]));
        }
    }
#pragma unroll
    for (int ks = 0; ks < 4; ++ks) {
#pragma unroll
        for (int p = 0; p < 2; ++p) {
            u32 a = ww[ks >> 1][2 * (ks & 1) + 0][p];
            u32 b = ww[ks >> 1][2 * (ks & 1) + 1][p];
            pl32(a, b);
            B[ks].w[p]     = a;
            B[ks].w[p + 2] = b;
        }
    }
}

__device__ __forceinline__ void pack_B1(const float p[9], int lo, FragU& B1) {
    if (lo == 0) {
        B1.w[0] = pkrtz(p[0], p[1]);
        B1.w[1] = pkrtz(p[2], p[3]);
        B1.w[2] = pkrtz(p[4], p[5]);
        B1.w[3] = pkrtz(p[6], p[7]);
    } else {
        B1.w[0] = pkrtz(p[8], 1.0f);     // k=9 slot multiplies the b1 column
        B1.w[1] = 0; B1.w[2] = 0; B1.w[3] = 0;
    }
}

__device__ __forceinline__ FragU lds_frag(const u32x4* wlds, int slot, int lane) {
    u32x4 v = wlds[slot * 64 + lane];
    FragU f;
    f.w[0] = v.x; f.w[1] = v.y; f.w[2] = v.z; f.w[3] = v.w;
    return f;
}

// Bias A-frag from a persistent register word (k_local=0 column only).
__device__ __forceinline__ FragU bias_frag(u32 w0) {
    FragU f;
    f.w[0] = w0; f.w[1] = 0; f.w[2] = 0; f.w[3] = 0;
    return f;
}

__global__ __launch_bounds__(256, 1) void srnet_mfma(
    const float* __restrict__ x_in,
    const float* __restrict__ sampler_w,
    const float* __restrict__ w1, const float* __restrict__ b1,
    const float* __restrict__ w2, const float* __restrict__ b2,
    const float* __restrict__ w3, const float* __restrict__ b3,
    const float* __restrict__ w4, const float* __restrict__ b4,
    const float* __restrict__ w5, const float* __restrict__ b5,
    const float* __restrict__ w6, const float* __restrict__ b6,
    float* __restrict__ out)
{
    constexpr int NG = 32258;        // (16*254*254)/32
    constexpr int OW = 1016;

    const int lane = threadIdx.x & 63;
    const int m    = lane & 31;
    const int lo   = lane >> 5;

    // ---- LDS: 38 weight b128 slots = 38912 B ----
    // slot 0..1: w1eff (b1 in k=9 col) | 2..33: hidden L*8+(mt*4+ks) | 34..37: w6
    __shared__ u32x4 wlds[38 * 64];

    const float* wptr[4] = { w2, w3, w4, w5 };
    for (int e = threadIdx.x; e < 2048; e += 256) {
        const int L  = e >> 9;
        const int f  = (e >> 6) & 7;
        const int l  = e & 63;
        const int mt = f >> 2, ks = f & 3;
        const float* src = wptr[L] + (32 * mt + (l & 31)) * 64 + 16 * ks + 8 * (l >> 5);
        const float4 f0 = *(const float4*)(src);
        const float4 f1 = *(const float4*)(src + 4);
        u32x4 v;
        v.x = pkrne(f0.x, f0.y); v.y = pkrne(f0.z, f0.w);
        v.z = pkrne(f1.x, f1.y); v.w = pkrne(f1.z, f1.w);
        wlds[(2 + L * 8 + f) * 64 + l] = v;
    }
    if (threadIdx.x < 64) {          // w6 frags (rows 16..31 zero)
        const int l = threadIdx.x, lm = l & 31, llo = l >> 5;
        const bool vr = (lm < 16);
        const int r6 = vr ? lm : 0;
#pragma unroll
        for (int ks = 0; ks < 4; ++ks) {
            const float* src = w6 + r6 * 64 + 16 * ks + 8 * llo;
            const float4 f0 = *(const float4*)(src);
            const float4 f1 = *(const float4*)(src + 4);
            u32x4 v;
            v.x = vr ? pkrne(f0.x, f0.y) : 0; v.y = vr ? pkrne(f0.z, f0.w) : 0;
            v.z = vr ? pkrne(f1.x, f1.y) : 0; v.w = vr ? pkrne(f1.z, f1.w) : 0;
            wlds[(34 + ks) * 64 + l] = v;
        }
    }
    if (threadIdx.x >= 64 && threadIdx.x < 128) {   // w1eff + b1 column
        const int l = threadIdx.x - 64, lm = l & 31, llo = l >> 5;
        float ws[4][9];
#pragma unroll
        for (int c = 0; c < 4; ++c) {
            float mx = sampler_w[c * 9];
#pragma unroll
            for (int k = 1; k < 9; ++k) mx = fmaxf(mx, sampler_w[c * 9 + k]);
            float e[9]; float sum = 0.f;
#pragma unroll
            for (int k = 0; k < 9; ++k) { e[k] = __expf(sampler_w[c * 9 + k] - mx); sum += e[k]; }
            float inv = 1.f / sum;
#pragma unroll
            for (int k = 0; k < 9; ++k) ws[c][k] = e[k] * inv;
        }
#pragma unroll
        for (int mt = 0; mt < 2; ++mt) {
            const int row = 32 * mt + lm;
            const float4 wr = *(const float4*)(w1 + row * 4);
            float we[9];
#pragma unroll
            for (int k = 0; k < 9; ++k)
                we[k] = wr.x * ws[0][k] + wr.y * ws[1][k] + wr.z * ws[2][k] + wr.w * ws[3][k];
            u32x4 v;
            if (llo == 0) {
                v.x = pkrne(we[0], we[1]); v.y = pkrne(we[2], we[3]);
                v.z = pkrne(we[4], we[5]); v.w = pkrne(we[6], we[7]);
            } else {
                v.x = pkrne(we[8], b1[row]);   // k=9 -> b1 column
                v.y = 0; v.z = 0; v.w = 0;
            }
            wlds[mt * 64 + l] = v;
        }
    }
    __syncthreads();

    // ---- persistent registers ----
    // Layers 2+3 weight frags hoisted once into 64 VGPRs (constant indices).
    FragU wreg[16];
#pragma unroll
    for (int f = 0; f < 16; ++f)
        wreg[f] = lds_frag(wlds, 2 + f, lane);

    u32 bfr[8];                       // bias A-frag words [L*2+mt]
#pragma unroll
    for (int L = 0; L < 4; ++L) {
        const float* bsrc = (L == 0) ? b2 : (L == 1) ? b3 : (L == 2) ? b4 : b5;
#pragma unroll
        for (int mt = 0; mt < 2; ++mt)
            bfr[L * 2 + mt] = (lo == 0) ? pkrne(bsrc[32 * mt + m], 0.f) : 0u;
    }
    FragU B4;                         // constant 5th-kstep B frag: k-row 0 = 1
    B4.w[0] = (lo == 0) ? pkrne(1.0f, 0.f) : 0u;
    B4.w[1] = 0; B4.w[2] = 0; B4.w[3] = 0;
    float b6r[8];
#pragma unroll
    for (int j = 0; j < 4; ++j) { b6r[j] = b6[4 * lo + j]; b6r[4 + j] = b6[8 + 4 * lo + j]; }
    const f32x16 z{};                 // zero C-tile

    // ---- group loop with cross-group patch prefetch ----
    const int wid = (int)((blockIdx.x * blockDim.x + threadIdx.x) >> 6);
    const int nw  = (int)((gridDim.x * blockDim.x) >> 6);

    int g = wid;
    float p[9];
    u32 oo = 0;
    if (g < NG) prep_group(x_in, g, m, lo, p, oo);

    while (g < NG) {
        const int gn = g + nw;
        // Block LICM of LDS weight frags across iterations (named locals
        // wreg/bfr/B4/b6r are unaffected and stay in registers).
        asm volatile("" ::: "memory");

        FragU B1;
        pack_B1(p, lo, B1);

        // prefetch next group's patches + out offset under this group's math
        float pn[9];
        u32 oon = 0;
        if (gn < NG) prep_group(x_in, gn, m, lo, pn, oon);

        f32x16 c0, c1;

        // ---- layer 1 (C = z; b1 rides the k=9 column) ----
        c0 = mfma16(lds_frag(wlds, 0, lane), B1, z);
        c1 = mfma16(lds_frag(wlds, 1, lane), B1, z);

        FragU B[4];
        epilogue(c0, c1, B);

        // ---- layers 2..3: weights from persistent registers ----
#pragma unroll
        for (int L = 0; L < 2; ++L) {
            c0 = mfma16(bias_frag(bfr[L * 2 + 0]), B4, z);
            c1 = mfma16(bias_frag(bfr[L * 2 + 1]), B4, z);
#pragma unroll
            for (int ks = 0; ks < 4; ++ks) {
                c0 = mfma16(wreg[L * 8 + ks],     B[ks], c0);
                c1 = mfma16(wreg[L * 8 + 4 + ks], B[ks], c1);
            }
            epilogue(c0, c1, B);
        }

        // ---- layers 4..5: weights from LDS ----
#pragma unroll
        for (int L = 2; L < 4; ++L) {
            c0 = mfma16(bias_frag(bfr[L * 2 + 0]), B4, z);
            c1 = mfma16(bias_frag(bfr[L * 2 + 1]), B4, z);
#pragma unroll
            for (int ks = 0; ks < 4; ++ks) {
                c0 = mfma16(lds_frag(wlds, 2 + L * 8 + ks,     lane), B[ks], c0);
                c1 = mfma16(lds_frag(wlds, 2 + L * 8 + 4 + ks, lane), B[ks], c1);
            }
            epilogue(c0, c1, B);
        }

        // ---- layer 6 (C = z; +b6 at store) ----
        c0 = mfma16(lds_frag(wlds, 34, lane), B[0], z);
#pragma unroll
        for (int ks = 1; ks < 4; ++ks)
            c0 = mfma16(lds_frag(wlds, 34 + ks, lane), B[ks], c0);

        // ---- pixel-shuffle store ----
        float* obase = out + oo;
        *(float4*)(obase)          = make_float4(c0[0] + b6r[0], c0[1] + b6r[1],
                                                 c0[2] + b6r[2], c0[3] + b6r[3]);
        *(float4*)(obase + 2 * OW) = make_float4(c0[4] + b6r[4], c0[5] + b6r[5],
                                                 c0[6] + b6r[6], c0[7] + b6r[7]);

        g = gn;
        oo = oon;
#pragma unroll
        for (int k = 0; k < 9; ++k) p[k] = pn[k];
    }
}

extern "C" void kernel_launch(void* const* d_in, const int* in_sizes, int n_in,
                              void* d_out, int out_size, void* d_ws, size_t ws_size,
                              hipStream_t stream)
{
    const float* x_in      = (const float*)d_in[0];
    const float* sampler_w = (const float*)d_in[1];
    // d_in[2] = sampler_b (reference multiplies it by 0 -> unused)
    const float* w1 = (const float*)d_in[3];
    const float* b1 = (const float*)d_in[4];
    const float* w2 = (const float*)d_in[5];
    const float* b2 = (const float*)d_in[6];
    const float* w3 = (const float*)d_in[7];
    const float* b3 = (const float*)d_in[8];
    const float* w4 = (const float*)d_in[9];
    const float* b4 = (const float*)d_in[10];
    const float* w5 = (const float*)d_in[11];
    const float* b5 = (const float*)d_in[12];
    const float* w6 = (const float*)d_in[13];
    const float* b6 = (const float*)d_in[14];
    float* out = (float*)d_out;

    dim3 grid(512);   // 2 blocks/CU -> 2 waves/SIMD at ~220 total regs
    dim3 block(256);
    hipLaunchKernelGGL(srnet_mfma, grid, block, 0, stream,
                       x_in, sampler_w, w1, b1, w2, b2, w3, b3,
                       w4, b4, w5, b5, w6, b6, out);
}

// Round 19
// 52.235 us; speedup vs baseline: 1.1173x; 1.1173x over previous
//
#include <hip/hip_runtime.h>

// SRNet via MFMA (v_mfma_f32_32x32x16_f16), D = W * X^T.
// Round 19: r12 (best, 52.5us: 52 VGPR + 48 acc = 100 <= 128-reg bin ->
// 4 waves/SIMD, grid 1024) + cross-group patch PREFETCH ONLY (+~12 regs,
// stays in the 128 bin). r18 bundled prefetch with a 64-reg weight hoist
// -> 160 regs -> 256 bin -> 2 waves -> 58us. Prefetch hides the 9-load
// L2 latency (~200-400cyc) that heads every group's dependency chain.

typedef _Float16 f16x8  __attribute__((ext_vector_type(8)));
typedef _Float16 half2v __attribute__((ext_vector_type(2)));
typedef float    f32x16 __attribute__((ext_vector_type(16)));
typedef unsigned int u32;
typedef u32 u32x4 __attribute__((ext_vector_type(4)));

union FragU { f16x8 v; u32 w[4]; };
union F4U  { u32x4 u; float f[4]; };

__device__ __forceinline__ u32 pkrne(float a, float b) {
    half2v h; h.x = (_Float16)a; h.y = (_Float16)b;
    return __builtin_bit_cast(u32, h);
}
__device__ __forceinline__ u32 pkrtz(float a, float b) {
    return __builtin_bit_cast(u32, __builtin_amdgcn_cvt_pkrtz(a, b));
}
__device__ __forceinline__ u32 pk_relu(u32 a) {
    half2v z = {};
    half2v r = __builtin_elementwise_max(__builtin_bit_cast(half2v, a), z);
    return __builtin_bit_cast(u32, r);
}

__device__ __forceinline__ f32x16 mfma16(const FragU& a, const FragU& b, f32x16 c) {
    return __builtin_amdgcn_mfma_f32_32x32x16_f16(a.v, b.v, c, 0, 0, 0);
}

__device__ __forceinline__ void pl32(u32& x, u32& y) {
    auto r = __builtin_amdgcn_permlane32_swap((int)x, (int)y, false, false);
    x = (u32)r[0]; y = (u32)r[1];
}

__device__ __forceinline__ void calc_coords(int g, int m, int& b, int& hp, int& wp) {
    unsigned P = (unsigned)(g * 32 + m);
    unsigned bb = P / 64516u;            // 254*254
    unsigned rem = P - bb * 64516u;
    unsigned h = rem / 254u;
    b = (int)bb; hp = (int)h; wp = (int)(rem - h * 254u);
}

__device__ __forceinline__ void prep_group(const float* __restrict__ x_in,
                                           int g, int m, int lo,
                                           float p[9], u32& ooff) {
    constexpr int OW = 1016;
    int b, hp, wp;
    calc_coords(g, m, b, hp, wp);
    const float* base = x_in + ((size_t)b << 16) + hp * 256 + wp;
#pragma unroll
    for (int i = 0; i < 3; ++i)
#pragma unroll
        for (int j = 0; j < 3; ++j)
            p[i * 3 + j] = base[i * 256 + j];
    ooff = (u32)b * (OW * OW) + (u32)(4 * hp + lo) * OW + 4 * wp;
}

// Init the 2 acc tiles with bias in D-layout (f32 LDS broadcast reads).
__device__ __forceinline__ void init_bias2(f32x16& a0, f32x16& a1,
                                           const u32x4* blds, int lo) {
#pragma unroll
    for (int mt = 0; mt < 2; ++mt) {
        f32x16& A = mt ? a1 : a0;
#pragma unroll
        for (int q = 0; q < 4; ++q) {
            F4U t; t.u = blds[8 * mt + 2 * q + lo];
            A[4 * q + 0] = t.f[0]; A[4 * q + 1] = t.f[1];
            A[4 * q + 2] = t.f[2]; A[4 * q + 3] = t.f[3];
        }
    }
}

// acc(2 tiles, D-layout, bias pre-added) -> relu -> f16 -> permlane -> B frags
__device__ __forceinline__ void epilogue(const f32x16& A0, const f32x16& A1,
                                         FragU (&B)[4]) {
    u32 ww[2][4][2];
#pragma unroll
    for (int mt = 0; mt < 2; ++mt) {
        const f32x16& A = mt ? A1 : A0;
#pragma unroll
        for (int q = 0; q < 4; ++q) {
            ww[mt][q][0] = pk_relu(pkrtz(A[4 * q + 0], A[4 * q + 1]));
            ww[mt][q][1] = pk_relu(pkrtz(A[4 * q + 2], A[4 * q + 3]));
        }
    }
#pragma unroll
    for (int ks = 0; ks < 4; ++ks) {
#pragma unroll
        for (int p = 0; p < 2; ++p) {
            u32 a = ww[ks >> 1][2 * (ks & 1) + 0][p];
            u32 b = ww[ks >> 1][2 * (ks & 1) + 1][p];
            pl32(a, b);
            B[ks].w[p]     = a;
            B[ks].w[p + 2] = b;
        }
    }
}

__device__ __forceinline__ void pack_B1(const float p[9], int lo, FragU& B1) {
    if (lo == 0) {
        B1.w[0] = pkrtz(p[0], p[1]);
        B1.w[1] = pkrtz(p[2], p[3]);
        B1.w[2] = pkrtz(p[4], p[5]);
        B1.w[3] = pkrtz(p[6], p[7]);
    } else {
        B1.w[0] = pkrtz(p[8], 0.0f);
        B1.w[1] = 0; B1.w[2] = 0; B1.w[3] = 0;
    }
}

__device__ __forceinline__ FragU lds_frag(const u32x4* wlds, int slot, int lane) {
    u32x4 v = wlds[slot * 64 + lane];
    FragU f;
    f.w[0] = v.x; f.w[1] = v.y; f.w[2] = v.z; f.w[3] = v.w;
    return f;
}

__global__ __launch_bounds__(256, 2) void srnet_mfma(
    const float* __restrict__ x_in,
    const float* __restrict__ sampler_w,
    const float* __restrict__ w1, const float* __restrict__ b1,
    const float* __restrict__ w2, const float* __restrict__ b2,
    const float* __restrict__ w3, const float* __restrict__ b3,
    const float* __restrict__ w4, const float* __restrict__ b4,
    const float* __restrict__ w5, const float* __restrict__ b5,
    const float* __restrict__ w6, const float* __restrict__ b6,
    float* __restrict__ out)
{
    constexpr int NG = 32258;        // (16*254*254)/32
    constexpr int OW = 1016;

    const int lane = threadIdx.x & 63;
    const int m    = lane & 31;
    const int lo   = lane >> 5;

    // ---- LDS: weight frag slots [38][64] of 16B + bias quads [84] ----
    // wlds slot 0..1: w1eff | 2..33: hidden L*8+(mt*4+ks) | 34..37: w6
    // blds quad: layer L base 16L (L=0..4 for b1..b5), b6 at 80..83
    __shared__ u32x4 wlds[38 * 64];
    __shared__ u32x4 blds[84];

    const float* wptr[4] = { w2, w3, w4, w5 };
    for (int e = threadIdx.x; e < 2048; e += 256) {
        const int L  = e >> 9;
        const int f  = (e >> 6) & 7;
        const int l  = e & 63;
        const int mt = f >> 2, ks = f & 3;
        const float* src = wptr[L] + (32 * mt + (l & 31)) * 64 + 16 * ks + 8 * (l >> 5);
        const float4 f0 = *(const float4*)(src);
        const float4 f1 = *(const float4*)(src + 4);
        u32x4 v;
        v.x = pkrne(f0.x, f0.y); v.y = pkrne(f0.z, f0.w);
        v.z = pkrne(f1.x, f1.y); v.w = pkrne(f1.z, f1.w);
        wlds[(2 + L * 8 + f) * 64 + l] = v;
    }
    if (threadIdx.x < 64) {          // w6 frags
        const int l = threadIdx.x, lm = l & 31, llo = l >> 5;
        const bool vr = (lm < 16);
        const int r6 = vr ? lm : 0;
#pragma unroll
        for (int ks = 0; ks < 4; ++ks) {
            const float* src = w6 + r6 * 64 + 16 * ks + 8 * llo;
            const float4 f0 = *(const float4*)(src);
            const float4 f1 = *(const float4*)(src + 4);
            u32x4 v;
            v.x = vr ? pkrne(f0.x, f0.y) : 0; v.y = vr ? pkrne(f0.z, f0.w) : 0;
            v.z = vr ? pkrne(f1.x, f1.y) : 0; v.w = vr ? pkrne(f1.z, f1.w) : 0;
            wlds[(34 + ks) * 64 + l] = v;
        }
    }
    if (threadIdx.x >= 64 && threadIdx.x < 128) {   // w1eff (softmax folded)
        const int l = threadIdx.x - 64, lm = l & 31, llo = l >> 5;
        float ws[4][9];
#pragma unroll
        for (int c = 0; c < 4; ++c) {
            float mx = sampler_w[c * 9];
#pragma unroll
            for (int k = 1; k < 9; ++k) mx = fmaxf(mx, sampler_w[c * 9 + k]);
            float e[9]; float sum = 0.f;
#pragma unroll
            for (int k = 0; k < 9; ++k) { e[k] = __expf(sampler_w[c * 9 + k] - mx); sum += e[k]; }
            float inv = 1.f / sum;
#pragma unroll
            for (int k = 0; k < 9; ++k) ws[c][k] = e[k] * inv;
        }
#pragma unroll
        for (int mt = 0; mt < 2; ++mt) {
            const int row = 32 * mt + lm;
            const float4 wr = *(const float4*)(w1 + row * 4);
            float we[9];
#pragma unroll
            for (int k = 0; k < 9; ++k)
                we[k] = wr.x * ws[0][k] + wr.y * ws[1][k] + wr.z * ws[2][k] + wr.w * ws[3][k];
            u32x4 v;
            if (llo == 0) {
                v.x = pkrne(we[0], we[1]); v.y = pkrne(we[2], we[3]);
                v.z = pkrne(we[4], we[5]); v.w = pkrne(we[6], we[7]);
            } else {
                v.x = pkrne(we[8], 0.f); v.y = 0; v.z = 0; v.w = 0;
            }
            wlds[mt * 64 + l] = v;
        }
    }
    for (int i = threadIdx.x; i < 336; i += 256) {   // biases as f32 quads
        float v;
        if      (i < 64)  v = b1[i];
        else if (i < 128) v = b2[i - 64];
        else if (i < 192) v = b3[i - 128];
        else if (i < 256) v = b4[i - 192];
        else if (i < 320) v = b5[i - 256];
        else              v = b6[i - 320];
        ((float*)blds)[i] = v;
    }
    __syncthreads();

    // ---- group loop: one pixel-group per wave, next-group patch prefetch ----
    const int wid = (int)((blockIdx.x * blockDim.x + threadIdx.x) >> 6);
    const int nw  = (int)((gridDim.x * blockDim.x) >> 6);

    int g = wid;
    float p[9];
    u32 oo = 0;
    if (g < NG) prep_group(x_in, g, m, lo, p, oo);

    while (g < NG) {
        const int gn = g + nw;
        // Block LICM across iterations (keeps weight frags out of VGPRs);
        // within the iteration the compiler batches/schedules the ds_reads.
        asm volatile("" ::: "memory");

        FragU B1;
        pack_B1(p, lo, B1);

        // prefetch next group's patches + out offset under this group's math
        float pn[9];
        u32 oon = 0;
        if (gn < NG) prep_group(x_in, gn, m, lo, pn, oon);

        f32x16 c0, c1;

        // ---- layer 1 ----
        init_bias2(c0, c1, blds + 0, lo);
        c0 = mfma16(lds_frag(wlds, 0, lane), B1, c0);
        c1 = mfma16(lds_frag(wlds, 1, lane), B1, c1);

        FragU B[4];
        epilogue(c0, c1, B);

        // ---- layers 2..5 ----
#pragma unroll
        for (int L = 0; L < 4; ++L) {
            init_bias2(c0, c1, blds + 16 * (L + 1), lo);
#pragma unroll
            for (int ks = 0; ks < 4; ++ks) {
                c0 = mfma16(lds_frag(wlds, 2 + L * 8 + ks,     lane), B[ks], c0);
                c1 = mfma16(lds_frag(wlds, 2 + L * 8 + 4 + ks, lane), B[ks], c1);
            }
            epilogue(c0, c1, B);
        }

        // ---- layer 6 (reuses c0; b6 C-init; rows 16..31 unused) ----
        {
            F4U t0; t0.u = blds[80 + lo];
            F4U t1; t1.u = blds[82 + lo];
#pragma unroll
            for (int j = 0; j < 4; ++j) {
                c0[j]      = t0.f[j];
                c0[4 + j]  = t1.f[j];
                c0[8 + j]  = 0.f;
                c0[12 + j] = 0.f;
            }
        }
#pragma unroll
        for (int ks = 0; ks < 4; ++ks)
            c0 = mfma16(lds_frag(wlds, 34 + ks, lane), B[ks], c0);

        // ---- pixel-shuffle store ----
        float* obase = out + oo;
        *(float4*)(obase)          = make_float4(c0[0], c0[1], c0[2], c0[3]);
        *(float4*)(obase + 2 * OW) = make_float4(c0[4], c0[5], c0[6], c0[7]);

        g = gn;
        oo = oon;
#pragma unroll
        for (int k = 0; k < 9; ++k) p[k] = pn[k];
    }
}

extern "C" void kernel_launch(void* const* d_in, const int* in_sizes, int n_in,
                              void* d_out, int out_size, void* d_ws, size_t ws_size,
                              hipStream_t stream)
{
    const float* x_in      = (const float*)d_in[0];
    const float* sampler_w = (const float*)d_in[1];
    // d_in[2] = sampler_b (reference multiplies it by 0 -> unused)
    const float* w1 = (const float*)d_in[3];
    const float* b1 = (const float*)d_in[4];
    const float* w2 = (const float*)d_in[5];
    const float* b2 = (const float*)d_in[6];
    const float* w3 = (const float*)d_in[7];
    const float* b3 = (const float*)d_in[8];
    const float* w4 = (const float*)d_in[9];
    const float* b4 = (const float*)d_in[10];
    const float* w5 = (const float*)d_in[11];
    const float* b5 = (const float*)d_in[12];
    const float* w6 = (const float*)d_in[13];
    const float* b6 = (const float*)d_in[14];
    float* out = (float*)d_out;

    dim3 grid(1024);  // 4 blocks/CU (LDS 4x40448 <= 163840; ~112 total regs)
    dim3 block(256);
    hipLaunchKernelGGL(srnet_mfma, grid, block, 0, stream,
                       x_in, sampler_w, w1, b1, w2, b2, w3, b3,
                       w4, b4, w5, b5, w6, b6, out);
}